// Round 4
// baseline (94.852 us; speedup 1.0000x reference)
//
#include <hip/hip_runtime.h>

constexpr int H = 512, W = 512;   // fixed by the problem (4,3,512,512)
constexpr int K = 5, PADR = 2;
constexpr int TR = 2;             // output rows per block
constexpr int SR = TR + 4;        // staged input rows (r0-2 .. r0+3)

__device__ __forceinline__ float rfl(float v) {
    union { float f; int i; } u; u.f = v;
    u.i = __builtin_amdgcn_readfirstlane(u.i);
    return u.f;
}

// map squared spatial distance {0,1,2,4,5,8} -> compact index 0..5
constexpr int idx6(int d2) {
    return d2 == 0 ? 0 : d2 == 1 ? 1 : d2 == 2 ? 2 : d2 == 4 ? 3 : d2 == 5 ? 4 : 5;
}

// DIAGNOSTIC ROUND: identical to the round-2 conflict-free kernel, but the
// compute phase runs TWICE (rep loop, #pragma unroll 1). The 2nd pass is
// bit-identical (c2r == c2 at runtime: 1.0f + 1e-30f == 1.0f) but the
// compiler cannot prove it (c2r symbolic in rep) and cannot hoist the LDS
// reads (rri laundered per-rep), and each rep's outputs feed asm volatile.
// Purpose: (a) dur_us delta == compute-phase time, (b) push the kernel's
// dispatch past the poison-fill durations so it finally appears in top-5
// WITH counters (VALUBusy / Occupancy / VGPR / FETCH / LDS-conflict).
__global__ __launch_bounds__(256, 4) void bilateral_kernel(
    const float* __restrict__ x,
    const float* __restrict__ sk,
    const float* __restrict__ sigma_color,
    float* __restrict__ out)
{
    __shared__ float lds[SR][W];      // 12 KB

    int t = threadIdx.x;
    int wv = t >> 6;
    int l = t & 63;

    // 6 distinct spatial weights by symmetry: d2 = {0,1,2,4,5,8} at flat
    // positions {12, 7, 6, 2, 1, 0}. log2 once, broadcast to SGPRs.
    float lw[6];
    lw[0] = rfl(__builtin_amdgcn_logf(sk[12]));
    lw[1] = rfl(__builtin_amdgcn_logf(sk[7]));
    lw[2] = rfl(__builtin_amdgcn_logf(sk[6]));
    lw[3] = rfl(__builtin_amdgcn_logf(sk[2]));
    lw[4] = rfl(__builtin_amdgcn_logf(sk[1]));
    lw[5] = rfl(__builtin_amdgcn_logf(sk[0]));
    float sk12 = rfl(sk[12]);         // center tap weight, exact (exp(0)=1)

    float s = sigma_color[0];                          // wave-uniform
    float c2 = -1.4426950408889634f / (2.0f * s * s);  // -log2(e)/(2s^2)

    int plane = blockIdx.x >> 8;           // 12 planes (B*C)
    int r0 = (blockIdx.x & 255) << 1;      // first output row of tile
    const float* xp = x + (size_t)plane * (H * W);

    // ---- stage 6 rows x 512 cols as 12 (row,half) units, 3 per wave.
#pragma unroll
    for (int su = 0; su < 3; ++su) {
        int u = wv + (su << 2);            // 0..11
        int k = u >> 1, hh = u & 1;
        int gr = r0 - 2 + k;               // np 'reflect': -1 -> 1, H -> H-2
        gr = (gr < 0) ? -gr : gr;
        gr = (gr >= H) ? (2 * H - 2 - gr) : gr;
        int col = (hh << 8) + (l << 2);
        float4 v = *(const float4*)(xp + (gr << 9) + col);
        *(float4*)(&lds[k][col]) = v;
    }
    __syncthreads();

    // ---- compute: wave wv -> output row r0+(wv>>1), chunk c = cols 4c..4c+3
    int rr = wv >> 1;
    int c  = ((wv & 1) << 6) + l;          // 0..127
    bool le = (c == 0), re = (c == 127);   // image edge chunks
    int cm1 = le ? 0   : c - 1;
    int cp1 = re ? 127 : c + 1;

    float ox[4];

#pragma unroll 1
    for (int rep = 0; rep < 2; ++rep) {
        // c2r == c2 bit-exactly at runtime, but symbolic to the compiler:
        // forces full recompute of the tap math on each rep.
        float c2r = c2 * (1.0f + (float)rep * 1e-30f);
        // launder the row index so LICM can't hoist the ds_reads out of
        // the rep loop (which would spike VGPR and poison the probe).
        int rri = rr;
        asm volatile("" : "+v"(rri));

        float cc[4], wsum[4], acc[4];
#pragma unroll
        for (int p = 0; p < 4; ++p) { wsum[p] = 0.f; acc[p] = 0.f; }

        constexpr int order[K] = {2, 0, 1, 3, 4};   // center row first
#pragma unroll
        for (int oi = 0; oi < K; ++oi) {
            const int i = order[oi];
            const float* rp = &lds[rri + i][0];

            float4 a = *(const float4*)(rp + (cm1 << 2));
            float4 m = *(const float4*)(rp + (c   << 2));
            float4 b = *(const float4*)(rp + (cp1 << 2));

            // window cols 4c-2 .. 4c+5
            float win[8];
            win[0] = le ? m.z : a.z;           // col -2 -> 2 at left edge
            win[1] = le ? m.y : a.w;           // col -1 -> 1
            win[2] = m.x; win[3] = m.y; win[4] = m.z; win[5] = m.w;
            win[6] = re ? m.z : b.x;           // col 512 -> 510 at right edge
            win[7] = re ? m.y : b.y;           // col 513 -> 509

            if (oi == 0) {                     // i==2: capture center pixels
#pragma unroll
                for (int p = 0; p < 4; ++p) cc[p] = win[p + 2];
            }

#pragma unroll
            for (int j = 0; j < K; ++j) {
                if (i == 2 && j == 2) {
                    // center tap: d=0, weight = sk[12] exactly
#pragma unroll
                    for (int p = 0; p < 4; ++p) {
                        wsum[p] += sk12;
                        acc[p] = __builtin_fmaf(sk12, cc[p], acc[p]);
                    }
                } else {
                    const float lwv = lw[idx6((i - 2) * (i - 2) + (j - 2) * (j - 2))];
#pragma unroll
                    for (int p = 0; p < 4; ++p) {
                        float v = win[p + j];
                        float d = v - cc[p];
                        float arg = __builtin_fmaf(d * c2r, d, lwv);
                        float wq = __builtin_amdgcn_exp2f(arg);
                        wsum[p] += wq;
                        acc[p] = __builtin_fmaf(wq, v, acc[p]);
                    }
                }
            }
        }

        float o0 = acc[0] * __builtin_amdgcn_rcpf(wsum[0] + 1e-8f);
        float o1 = acc[1] * __builtin_amdgcn_rcpf(wsum[1] + 1e-8f);
        float o2 = acc[2] * __builtin_amdgcn_rcpf(wsum[2] + 1e-8f);
        float o3 = acc[3] * __builtin_amdgcn_rcpf(wsum[3] + 1e-8f);
        // keep this rep's results live (prevents folding the two reps)
        asm volatile("" :: "v"(o0), "v"(o1), "v"(o2), "v"(o3));
        ox[0] = o0; ox[1] = o1; ox[2] = o2; ox[3] = o3;
    }

    float* op = out + (size_t)plane * (H * W) + ((size_t)(r0 + rr) << 9) + (c << 2);
    float4 o;
    o.x = ox[0]; o.y = ox[1]; o.z = ox[2]; o.w = ox[3];
    *(float4*)op = o;
}

extern "C" void kernel_launch(void* const* d_in, const int* in_sizes, int n_in,
                              void* d_out, int out_size, void* d_ws, size_t ws_size,
                              hipStream_t stream) {
    const float* x  = (const float*)d_in[0];
    const float* sk = (const float*)d_in[1];
    const float* sc = (const float*)d_in[2];
    float* out = (float*)d_out;

    const int total = in_sizes[0];              // 3,145,728 elements
    const int blocks = total / (256 * 4);       // 3072 = 12 planes * 256 tiles
    bilateral_kernel<<<blocks, 256, 0, stream>>>(x, sk, sc, out);
}

// Round 5
// 77.105 us; speedup vs baseline: 1.2302x; 1.2302x over previous
//
#include <hip/hip_runtime.h>

typedef float v2f __attribute__((ext_vector_type(2)));

constexpr int H = 512, W = 512;   // fixed by the problem (4,3,512,512)
constexpr int K = 5;
constexpr int TR = 4;             // output rows per block
constexpr int SR = TR + 4;        // staged input rows (r0-2 .. r0+5)

__device__ __forceinline__ float rfl(float v) {
    union { float f; int i; } u; u.f = v;
    u.i = __builtin_amdgcn_readfirstlane(u.i);
    return u.f;
}

// map squared spatial distance {0,1,2,4,5,8} -> compact index 0..5
constexpr int idx6(int d2) {
    return d2 == 0 ? 0 : d2 == 1 ? 1 : d2 == 2 ? 2 : d2 == 4 ? 3 : d2 == 5 ? 4 : 5;
}

// Round-2 conflict-free structure + two changes driven by the round-3 probe
// (compute phase measured at 12.7 us, VALU-issue-bound):
//  1. Packed f32 math: the 4 px/lane are processed as two float2 pairs ->
//     v_pk_fma_f32/v_pk_add_f32/v_pk_mul_f32 halve VALU issue. exp stays
//     scalar (no packed trans). Bit-identical numerics.
//  2. Block = 4 output rows (stage 8 rows, 16 KB LDS), wave does two
//     (row,half) tasks -> halo read amplification 3x -> 2x, 1536 blocks.
__global__ __launch_bounds__(256, 4) void bilateral_kernel(
    const float* __restrict__ x,
    const float* __restrict__ sk,
    const float* __restrict__ sigma_color,
    float* __restrict__ out)
{
    __shared__ float lds[SR][W];      // 16 KB

    int t = threadIdx.x;
    int wv = t >> 6;
    int l = t & 63;

    // 6 distinct spatial weights by symmetry: d2 = {0,1,2,4,5,8} at flat
    // positions {12, 7, 6, 2, 1, 0}. log2 once, broadcast to SGPRs.
    float lw[6];
    lw[0] = rfl(__builtin_amdgcn_logf(sk[12]));
    lw[1] = rfl(__builtin_amdgcn_logf(sk[7]));
    lw[2] = rfl(__builtin_amdgcn_logf(sk[6]));
    lw[3] = rfl(__builtin_amdgcn_logf(sk[2]));
    lw[4] = rfl(__builtin_amdgcn_logf(sk[1]));
    lw[5] = rfl(__builtin_amdgcn_logf(sk[0]));
    float sk12 = rfl(sk[12]);         // center tap weight, exact (exp(0)=1)

    float s = sigma_color[0];                          // wave-uniform
    float c2 = -1.4426950408889634f / (2.0f * s * s);  // -log2(e)/(2s^2)
    v2f c2v   = { c2, c2 };
    v2f sk12v = { sk12, sk12 };

    int plane = blockIdx.x >> 7;           // 12 planes (B*C)
    int r0 = (blockIdx.x & 127) << 2;      // first output row of tile
    const float* xp = x + (size_t)plane * (H * W);
    float* outp = out + (size_t)plane * (H * W);

    // ---- stage 8 rows x 512 cols as 16 (row,half) units, 4 per wave.
    // Each unit: 64 lanes x float4, global coalesced, LDS write stride 16 B.
#pragma unroll
    for (int su = 0; su < 4; ++su) {
        int u = wv + (su << 2);            // 0..15
        int k = u >> 1, hh = u & 1;
        int gr = r0 - 2 + k;               // np 'reflect': -1 -> 1, H -> H-2
        gr = (gr < 0) ? -gr : gr;
        gr = (gr >= H) ? (2 * H - 2 - gr) : gr;
        int col = (hh << 8) + (l << 2);
        *(float4*)(&lds[k][col]) = *(const float4*)(xp + (gr << 9) + col);
    }
    __syncthreads();

    // ---- compute: 8 tasks (4 rows x 2 halves); wave wv -> tasks wv, wv+4
#pragma unroll
    for (int ti = 0; ti < 2; ++ti) {
        int tk = wv + (ti << 2);           // 0..7
        int rr = tk >> 1, hh = tk & 1;     // output row r0+rr, half hh
        int c  = (hh << 6) + l;            // chunk: cols 4c..4c+3
        bool le = (c == 0), re = (c == 127);
        int cm1 = le ? 0   : c - 1;
        int cp1 = re ? 127 : c + 1;

        v2f cc0, cc1, ws0, ws1, ac0, ac1;
        ws0 = ws1 = ac0 = ac1 = (v2f){0.f, 0.f};
        cc0 = cc1 = (v2f){0.f, 0.f};

        constexpr int order[K] = {2, 0, 1, 3, 4};   // center row first
#pragma unroll
        for (int oi = 0; oi < K; ++oi) {
            const int i = order[oi];
            const float* rp = &lds[rr + i][0];

            float4 a = *(const float4*)(rp + (cm1 << 2));
            float4 m = *(const float4*)(rp + (c   << 2));
            float4 b = *(const float4*)(rp + (cp1 << 2));

            // window cols 4c-2 .. 4c+5
            float win[8];
            win[0] = le ? m.z : a.z;       // col -2 -> 2 at left edge
            win[1] = le ? m.y : a.w;       // col -1 -> 1
            win[2] = m.x; win[3] = m.y; win[4] = m.z; win[5] = m.w;
            win[6] = re ? m.z : b.x;       // col 512 -> 510 at right edge
            win[7] = re ? m.y : b.y;       // col 513 -> 509

            if (oi == 0) {                 // i==2: capture center pixels
                cc0 = (v2f){ win[2], win[3] };
                cc1 = (v2f){ win[4], win[5] };
            }

#pragma unroll
            for (int j = 0; j < K; ++j) {
                if (i == 2 && j == 2) {
                    // center tap: d=0, weight = sk[12] exactly
                    ws0 += sk12v;
                    ws1 += sk12v;
                    ac0 = __builtin_elementwise_fma(sk12v, cc0, ac0);
                    ac1 = __builtin_elementwise_fma(sk12v, cc1, ac1);
                } else {
                    const float lwv = lw[idx6((i - 2) * (i - 2) + (j - 2) * (j - 2))];
                    v2f lsp = { lwv, lwv };
                    v2f v0 = { win[j],     win[j + 1] };
                    v2f v1 = { win[j + 2], win[j + 3] };
                    v2f d0 = v0 - cc0;
                    v2f d1 = v1 - cc1;
                    v2f g0 = __builtin_elementwise_fma(d0 * c2v, d0, lsp);
                    v2f g1 = __builtin_elementwise_fma(d1 * c2v, d1, lsp);
                    v2f w0, w1;
                    w0[0] = __builtin_amdgcn_exp2f(g0[0]);
                    w0[1] = __builtin_amdgcn_exp2f(g0[1]);
                    w1[0] = __builtin_amdgcn_exp2f(g1[0]);
                    w1[1] = __builtin_amdgcn_exp2f(g1[1]);
                    ws0 += w0;
                    ws1 += w1;
                    ac0 = __builtin_elementwise_fma(w0, v0, ac0);
                    ac1 = __builtin_elementwise_fma(w1, v1, ac1);
                }
            }
        }

        float4 o;
        o.x = ac0[0] * __builtin_amdgcn_rcpf(ws0[0] + 1e-8f);
        o.y = ac0[1] * __builtin_amdgcn_rcpf(ws0[1] + 1e-8f);
        o.z = ac1[0] * __builtin_amdgcn_rcpf(ws1[0] + 1e-8f);
        o.w = ac1[1] * __builtin_amdgcn_rcpf(ws1[1] + 1e-8f);
        *(float4*)(outp + ((size_t)(r0 + rr) << 9) + (c << 2)) = o;
    }
}

extern "C" void kernel_launch(void* const* d_in, const int* in_sizes, int n_in,
                              void* d_out, int out_size, void* d_ws, size_t ws_size,
                              hipStream_t stream) {
    const float* x  = (const float*)d_in[0];
    const float* sk = (const float*)d_in[1];
    const float* sc = (const float*)d_in[2];
    float* out = (float*)d_out;

    const int total = in_sizes[0];              // 3,145,728 elements
    const int blocks = total / (256 * 8);       // 1536 = 12 planes * 128 tiles
    bilateral_kernel<<<blocks, 256, 0, stream>>>(x, sk, sc, out);
}